// Round 4
// baseline (152.890 us; speedup 1.0000x reference)
//
#include <hip/hip_runtime.h>

typedef __bf16 bf16;
typedef __bf16 bf16x8 __attribute__((ext_vector_type(8)));
typedef float f32x4 __attribute__((ext_vector_type(4)));
typedef unsigned short u16;
typedef u16 u16x8 __attribute__((ext_vector_type(8)));
typedef unsigned int u32;

#define BATCH 64
#define NODES 512
#define AMINO 64
#define NTYPES 20
#define RMAX 13
#define NJT 26           // 26 j-tiles of 16
#define PADA 72          // padded amino stride in LDS planes (elements)
#define CROWF 100        // cbuf row in floats (96 + 4 pad; 400 B, 16B-aligned)

__constant__ int c_res_lens[NTYPES] = {4,10,7,7,5,8,8,3,9,7,7,8,7,10,6,5,6,13,11,6};

// fp32 -> bf16, exact round-to-nearest-even, pure bit ops
__device__ __forceinline__ u16 f2bf(float f) {
    u32 u; __builtin_memcpy(&u, &f, 4);
    u32 r = u + 0x7FFFu + ((u >> 16) & 1u);
    return (u16)(r >> 16);
}

// int64 vs int32 probe for type_ids: odd words all-zero <=> int64 high halves.
__device__ __forceinline__ int detect_i64(const int* __restrict__ p) {
    int z = 0;
#pragma unroll
    for (int k = 0; k < 16; ++k) z |= p[2 * k + 1];
    return z == 0;
}
__device__ __forceinline__ int tid_at(const int* __restrict__ p, int n, int is64) {
    return p[is64 ? 2 * n : n];
}

// ---------------- prep kernel ----------------
// blocks 0..259: swizzle fp32 W into B-fragment-linear bf16 layout:
//   chunk = (t*NJT + jt)*2 + kh ; lane l holds W[t][a=kh*32+(l>>4)*8+i][j=jt*16+(l&15)]
// block 260: exclusive prefix sum of residue lengths -> S[0..511]
__global__ __launch_bounds__(256) void prep_kernel(const float* __restrict__ W,
                                                   const int* __restrict__ type_ids,
                                                   u16* __restrict__ wswz,
                                                   int* __restrict__ S) {
    if (blockIdx.x < 260) {
        int g = blockIdx.x * 256 + threadIdx.x;     // over 20*26*2*64 = 66560 lanes
        if (g >= NTYPES * NJT * 2 * 64) return;
        int lane = g & 63;
        int chunk = g >> 6;
        int kh = chunk & 1;
        int tj = chunk >> 1;
        int t = tj / NJT;
        int jt = tj - t * NJT;
        int q = lane >> 4, c = lane & 15;
        int a0 = kh * 32 + q * 8;
        int j = jt * 16 + c;
        u16x8 v;
#pragma unroll
        for (int i = 0; i < 8; ++i)
            v[i] = f2bf(W[(size_t)(t * AMINO + a0 + i) * (RMAX * 32) + j]);
        *(u16x8*)(wswz + (size_t)chunk * 512 + lane * 8) = v;
    } else {
        __shared__ int s[256];
        int is64 = detect_i64(type_ids);
        int i = threadIdx.x;
        int la = c_res_lens[tid_at(type_ids, 2 * i, is64)];
        int lb = c_res_lens[tid_at(type_ids, 2 * i + 1, is64)];
        s[i] = la + lb;
        __syncthreads();
        for (int off = 1; off < 256; off <<= 1) {
            int v = (i >= off) ? s[i - off] : 0;
            __syncthreads();
            s[i] += v;
            __syncthreads();
        }
        int excl = s[i] - (la + lb);     // exclusive over pairs
        S[2 * i] = excl;
        S[2 * i + 1] = excl + la;
    }
}

// ---------------- main kernel ----------------
// one block per node; 4 waves; wave w handles residues r = w, w+4, ...
__global__ __launch_bounds__(256) void main_kernel(const float* __restrict__ x,
                                                   const int* __restrict__ type_ids,
                                                   const int* __restrict__ S,
                                                   const u16* __restrict__ wswz,
                                                   float* __restrict__ out,
                                                   int G) {
    __shared__ __align__(16) u16 planes[3 * BATCH * PADA];     // [v][b][a pad72] 27648 B
    __shared__ __align__(16) float cbuff[4][16 * CROWF];       // per-wave fp32 C staging

    const int n = blockIdx.x;
    const int tid = threadIdx.x;
    const int is64 = detect_i64(type_ids);
    const int t = tid_at(type_ids, n, is64);
    const int len = c_res_lens[t];
    const int s0 = S[n];

    // ---- stage x[.,n,.,.] (fp32) into bf16 v-planes ----
#pragma unroll
    for (int it = 0; it < 12; ++it) {
        int E = (tid + it * 256) * 4;        // flat elem over (b,a,v): 64*192
        int b = E / 192;
        int rem = E - b * 192;
        f32x4 v4 = *(const f32x4*)(x + (size_t)(b * NODES + n) * 192 + rem);
#pragma unroll
        for (int i = 0; i < 4; ++i) {
            int e = rem + i;
            int a = e / 3;
            int vv = e - a * 3;
            planes[vv * (BATCH * PADA) + b * PADA + a] = f2bf(v4[i]);
        }
    }
    __syncthreads();

    const int w = tid >> 6;
    const int l = tid & 63;
    const int q = l >> 4;
    const int c = l & 15;

    // ---- preload all A fragments: lane holds A[b=m*16+c][a=kh*32+q*8+i] ----
    union Frag { u16x8 u; bf16x8 b; };
    Frag Af[4][3][2];
#pragma unroll
    for (int m = 0; m < 4; ++m)
#pragma unroll
        for (int v = 0; v < 3; ++v)
#pragma unroll
            for (int kh = 0; kh < 2; ++kh)
                Af[m][v][kh].u = *(const u16x8*)(planes + v * (BATCH * PADA) +
                                                 (m * 16 + c) * PADA + kh * 32 + q * 8);

    float* cb = cbuff[w];

    for (int r = w; r < len; r += 4) {
        Frag Bf[2][2];
#pragma unroll
        for (int jj = 0; jj < 2; ++jj)
#pragma unroll
            for (int kh = 0; kh < 2; ++kh)
                Bf[jj][kh].u = *(const u16x8*)(wswz +
                                (size_t)((t * NJT + (2 * r + jj)) * 2 + kh) * 512 + l * 8);

        const int g = s0 + r;   // output row index within G

#pragma unroll 1
        for (int m = 0; m < 4; ++m) {
            f32x4 acc[2][3];
            const f32x4 z = {0.f, 0.f, 0.f, 0.f};
#pragma unroll
            for (int jj = 0; jj < 2; ++jj)
#pragma unroll
                for (int v = 0; v < 3; ++v) {
                    f32x4 a0 = __builtin_amdgcn_mfma_f32_16x16x32_bf16(Af[m][v][0].b, Bf[jj][0].b, z, 0, 0, 0);
                    acc[jj][v] = __builtin_amdgcn_mfma_f32_16x16x32_bf16(Af[m][v][1].b, Bf[jj][1].b, a0, 0, 0, 0);
                }

            // stage fp32 C tile: rows b_local = q*4+reg, cols atom*3+v
#pragma unroll
            for (int jj = 0; jj < 2; ++jj)
#pragma unroll
                for (int v = 0; v < 3; ++v)
#pragma unroll
                    for (int reg = 0; reg < 4; ++reg)
                        cb[(q * 4 + reg) * CROWF + (jj * 16 + c) * 3 + v] =
                            acc[jj][v][reg];

            asm volatile("" ::: "memory");   // keep uint4 reads after float writes

            // coalesced copy out: 16 rows x 384 B contiguous each (24 x 16B per row)
#pragma unroll
            for (int it2 = 0; it2 < 6; ++it2) {
                int ck = it2 * 64 + l;       // [0, 384)
                int row = ck / 24;
                int c16 = ck - row * 24;
                uint4 d = *(const uint4*)((const char*)cb + row * (CROWF * 4) + c16 * 16);
                *(uint4*)((char*)out +
                          ((size_t)(m * 16 + row) * G + g) * 384 + c16 * 16) = d;
            }

            asm volatile("" ::: "memory");   // reads done before next m overwrites
        }
    }
}

extern "C" void kernel_launch(void* const* d_in, const int* in_sizes, int n_in,
                              void* d_out, int out_size, void* d_ws, size_t ws_size,
                              hipStream_t stream) {
    const float* x = (const float*)d_in[0];    // fp32 (B, N, 64, 3)
    const float* W = (const float*)d_in[1];    // fp32 (20, 64, 416)
    const int* type_ids = (const int*)d_in[2]; // int32 or int64 (autodetected), 512
    int G = out_size / (BATCH * 32 * 3);       // valid (node,residue) rows

    int* S = (int*)d_ws;                                   // 512 ints
    u16* wswz = (u16*)((char*)d_ws + 4096);                // 20*26*2*512 bf16 ≈ 1.06 MB

    prep_kernel<<<261, 256, 0, stream>>>(W, type_ids, wswz, S);
    main_kernel<<<NODES, 256, 0, stream>>>(x, type_ids, S, wswz, (float*)d_out, G);
}

// Round 5
// 127.588 us; speedup vs baseline: 1.1983x; 1.1983x over previous
//
#include <hip/hip_runtime.h>

typedef __bf16 bf16;
typedef __bf16 bf16x8 __attribute__((ext_vector_type(8)));
typedef float f32x4 __attribute__((ext_vector_type(4)));
typedef unsigned short u16;
typedef u16 u16x8 __attribute__((ext_vector_type(8)));
typedef unsigned int u32;

#define BATCH 64
#define NODES 512
#define AMINO 64
#define NTYPES 20
#define RMAX 13
#define NJT 26           // 26 j-tiles of 16
#define PADA 72          // padded amino stride in LDS planes (elements)

__constant__ int c_res_lens[NTYPES] = {4,10,7,7,5,8,8,3,9,7,7,8,7,10,6,5,6,13,11,6};

// fp32 -> bf16, exact round-to-nearest-even, pure bit ops
__device__ __forceinline__ u16 f2bf(float f) {
    u32 u; __builtin_memcpy(&u, &f, 4);
    u32 r = u + 0x7FFFu + ((u >> 16) & 1u);
    return (u16)(r >> 16);
}

// int64 vs int32 probe for type_ids: odd words all-zero <=> int64 high halves.
__device__ __forceinline__ int detect_i64(const int* __restrict__ p) {
    int z = 0;
#pragma unroll
    for (int k = 0; k < 16; ++k) z |= p[2 * k + 1];
    return z == 0;
}
__device__ __forceinline__ int tid_at(const int* __restrict__ p, int n, int is64) {
    return p[is64 ? 2 * n : n];
}

// ---------------- prep kernel ----------------
// blocks 0..259: swizzle fp32 W into B-fragment-linear bf16 layout:
//   chunk = (t*NJT + jt)*2 + kh ; lane l holds W[t][a=kh*32+(l>>4)*8+i][j=jt*16+(l&15)]
// block 260: exclusive prefix sum of residue lengths -> S[0..511]
__global__ __launch_bounds__(256) void prep_kernel(const float* __restrict__ W,
                                                   const int* __restrict__ type_ids,
                                                   u16* __restrict__ wswz,
                                                   int* __restrict__ S) {
    if (blockIdx.x < 260) {
        int g = blockIdx.x * 256 + threadIdx.x;     // over 20*26*2*64 = 66560 lanes
        if (g >= NTYPES * NJT * 2 * 64) return;
        int lane = g & 63;
        int chunk = g >> 6;
        int kh = chunk & 1;
        int tj = chunk >> 1;
        int t = tj / NJT;
        int jt = tj - t * NJT;
        int q = lane >> 4, c = lane & 15;
        int a0 = kh * 32 + q * 8;
        int j = jt * 16 + c;
        u16x8 v;
#pragma unroll
        for (int i = 0; i < 8; ++i)
            v[i] = f2bf(W[(size_t)(t * AMINO + a0 + i) * (RMAX * 32) + j]);
        *(u16x8*)(wswz + (size_t)chunk * 512 + lane * 8) = v;
    } else {
        __shared__ int s[256];
        int is64 = detect_i64(type_ids);
        int i = threadIdx.x;
        int la = c_res_lens[tid_at(type_ids, 2 * i, is64)];
        int lb = c_res_lens[tid_at(type_ids, 2 * i + 1, is64)];
        s[i] = la + lb;
        __syncthreads();
        for (int off = 1; off < 256; off <<= 1) {
            int v = (i >= off) ? s[i - off] : 0;
            __syncthreads();
            s[i] += v;
            __syncthreads();
        }
        int excl = s[i] - (la + lb);     // exclusive over pairs
        S[2 * i] = excl;
        S[2 * i + 1] = excl + la;
    }
}

// ---------------- main kernel ----------------
// block = (node n, m-tile m): 16 batches. 4 waves; wave w handles r = w, w+4, ...
__global__ __launch_bounds__(256) void main_kernel(const float* __restrict__ x,
                                                   const int* __restrict__ type_ids,
                                                   const int* __restrict__ S,
                                                   const u16* __restrict__ wswz,
                                                   float* __restrict__ out,
                                                   int G) {
    __shared__ __align__(16) u16 planes[3][16][PADA];   // [v][b16][a pad72] = 6912 B

    const int bid = blockIdx.x;
    const int n = bid >> 2;
    const int m = bid & 3;
    const int tid = threadIdx.x;
    const int w = tid >> 6;
    const int l = tid & 63;

    const int is64 = detect_i64(type_ids);
    const int t = tid_at(type_ids, n, is64);
    const int len = c_res_lens[t];
    const int s0 = S[n];

    // ---- stage x[m*16..m*16+15, n, :, :] into bf16 v-planes ----
    // wave w, iter i -> batch row b16 = i*4 + w; lane l -> amino a = l.
#pragma unroll
    for (int i = 0; i < 4; ++i) {
        int b16 = i * 4 + w;
        const float* src = x + ((size_t)(m * 16 + b16) * NODES + n) * 192 + l * 3;
        float v0 = src[0];
        float v1 = src[1];
        float v2 = src[2];
        planes[0][b16][l] = f2bf(v0);
        planes[1][b16][l] = f2bf(v1);
        planes[2][b16][l] = f2bf(v2);
    }
    __syncthreads();

    const int q = l >> 4;
    const int c = l & 15;

    // ---- preload A fragments: lane holds A[row=c][k=kh*32+q*8+i] ----
    union Frag { u16x8 u; bf16x8 b; };
    Frag Af[3][2];
#pragma unroll
    for (int v = 0; v < 3; ++v)
#pragma unroll
        for (int kh = 0; kh < 2; ++kh)
            Af[v][kh].u = *(const u16x8*)(&planes[v][c][kh * 32 + q * 8]);

    for (int r = w; r < len; r += 4) {
        Frag Bf[2][2];
#pragma unroll
        for (int jj = 0; jj < 2; ++jj)
#pragma unroll
            for (int kh = 0; kh < 2; ++kh)
                Bf[jj][kh].u = *(const u16x8*)(wswz +
                                (size_t)((t * NJT + (2 * r + jj)) * 2 + kh) * 512 + l * 8);

        const int g = s0 + r;   // output row index within G

        f32x4 acc[2][3];
        const f32x4 z = {0.f, 0.f, 0.f, 0.f};
#pragma unroll
        for (int jj = 0; jj < 2; ++jj)
#pragma unroll
            for (int v = 0; v < 3; ++v) {
                f32x4 a0 = __builtin_amdgcn_mfma_f32_16x16x32_bf16(Af[v][0].b, Bf[jj][0].b, z, 0, 0, 0);
                acc[jj][v] = __builtin_amdgcn_mfma_f32_16x16x32_bf16(Af[v][1].b, Bf[jj][1].b, a0, 0, 0, 0);
            }

        // direct store: lane writes 3 consecutive fp32 (v=0..2) per (row, atom);
        // 16 lanes (c) cover 192 B contiguous per (q, reg, jj) segment.
#pragma unroll
        for (int reg = 0; reg < 4; ++reg) {
            float* rowp = out + ((size_t)(m * 16 + q * 4 + reg) * G + g) * 96;
#pragma unroll
            for (int jj = 0; jj < 2; ++jj) {
                float* p = rowp + (jj * 16 + c) * 3;
                p[0] = acc[jj][0][reg];
                p[1] = acc[jj][1][reg];
                p[2] = acc[jj][2][reg];
            }
        }
    }
}

extern "C" void kernel_launch(void* const* d_in, const int* in_sizes, int n_in,
                              void* d_out, int out_size, void* d_ws, size_t ws_size,
                              hipStream_t stream) {
    const float* x = (const float*)d_in[0];    // fp32 (B, N, 64, 3)
    const float* W = (const float*)d_in[1];    // fp32 (20, 64, 416)
    const int* type_ids = (const int*)d_in[2]; // int32 or int64 (autodetected), 512
    int G = out_size / (BATCH * 32 * 3);       // valid (node,residue) rows

    int* S = (int*)d_ws;                                   // 512 ints
    u16* wswz = (u16*)((char*)d_ws + 4096);                // 20*26*2*512 bf16 ≈ 1.06 MB

    prep_kernel<<<261, 256, 0, stream>>>(W, type_ids, wswz, S);
    main_kernel<<<NODES * 4, 256, 0, stream>>>(x, type_ids, S, wswz, (float*)d_out, G);
}